// Round 2
// baseline (739.892 us; speedup 1.0000x reference)
//
#include <hip/hip_runtime.h>
#include <cstdint>

typedef unsigned short u16;

#define NB 2
#define NL 12
#define NN_ 2048
#define NH 64
#define NF 116
constexpr size_t NSQ = (size_t)NN_ * NN_;
constexpr size_t OUT_PER = (size_t)NB * NN_ * 3 * NN_;  // one output tensor (B,N,3N) elems

__device__ __forceinline__ u16 f2bf(float f) {
    union { float f; unsigned u; } v; v.f = f;
    unsigned r = 0x7FFFu + ((v.u >> 16) & 1u);
    return (u16)((v.u + r) >> 16);
}

// ---------------------------------------------------------------------------
// Kernel 1: per-(b,n) feature MLP -> Q/K vectors (fp32) for both adjacencies.
// qk layout: [(a*2 + qsel)][b][n][h], qsel 0=Q 1=K.  One 128-thr block per row.
// ---------------------------------------------------------------------------
__global__ __launch_bounds__(128) void feat_kernel(
    const float* __restrict__ hist, const float* __restrict__ embd, const float* __restrict__ embu,
    const float* __restrict__ tid, const float* __restrict__ diw,
    const float* __restrict__ W1, const float* __restrict__ b1,
    const float* __restrict__ gamma, const float* __restrict__ beta,
    const float* __restrict__ mean, const float* __restrict__ var,
    const float* __restrict__ W2, const float* __restrict__ b2,
    const float* __restrict__ WQ, const float* __restrict__ WK,
    float* __restrict__ qk) {
    int bn = blockIdx.x;
    int b = bn >> 11, n = bn & (NN_ - 1);
    __shared__ float X[NL];
    __shared__ float hsh[128];
    __shared__ float feat[84];
    int t = threadIdx.x;
    if (t < NL) X[t] = hist[((size_t)(b * NL + t) * NN_ + n) * 3];
    __syncthreads();
    // h = BN(relu(W1 @ x + b1))
    float acc = b1[t];
#pragma unroll
    for (int l = 0; l < NL; ++l) acc += X[l] * W1[t * NL + l];
    acc = fmaxf(acc, 0.f);
    acc = (acc - mean[t]) * rsqrtf(var[t] + 1e-5f) * gamma[t] + beta[t];
    hsh[t] = acc;
    __syncthreads();
    if (t < 64) {
        float d = b2[t];
#pragma unroll 8
        for (int j = 0; j < 128; ++j) d += hsh[j] * W2[t * 128 + j];
        feat[t] = d;
    } else {
        int u = t - 64;
        if (u < 10) feat[64 + u] = tid[((size_t)(b * NL + (NL - 1)) * NN_ + n) * 10 + u];
        else if (u < 20) feat[64 + u] = diw[((size_t)(b * NL + (NL - 1)) * NN_ + n) * 10 + (u - 10)];
    }
    __syncthreads();
    // Q/K: threads 0..63 -> WQ, 64..127 -> WK. Shared first-84 part, emb part per adjacency.
    const float* W = (t < 64) ? WQ : WK;
    int row = t & 63;
    float s = 0.f;
    for (int f = 0; f < 84; ++f) s += feat[f] * W[row * NF + f];
    float s1 = s, s2 = s;
    for (int u2 = 0; u2 < 32; ++u2) {
        float w = W[row * NF + 84 + u2];
        s1 += w * embd[n * 32 + u2];
        s2 += w * embu[n * 32 + u2];
    }
    int qsel = (t < 64) ? 0 : 1;
    const size_t MS = (size_t)NB * NN_ * NH;
    size_t base = ((size_t)b * NN_ + n) * NH + row;
    qk[(size_t)(0 * 2 + qsel) * MS + base] = s1;
    qk[(size_t)(1 * 2 + qsel) * MS + base] = s2;
}

// ---------------------------------------------------------------------------
// Kernel 2: fused scores + softmax + mask + row-normalize.
// Softmax denom cancels with row-norm: A = w / sum(w), w = (mask+1e-7)*exp(s-max).
// Writes G (bf16, with diagonal, for the MFMA matmul) AND the first-order
// localized outputs (fp32, 3 copies, diag zeroed) directly.
// Block: 32 rows x 2048 cols; 256 thr; thread tile 4 rows x 4 cols.
// Two passes (online max/sum, then recompute+write) -> no score storage.
// ---------------------------------------------------------------------------
__device__ __forceinline__ void score_tile(const float (*Qs)[68], const float (*Ks)[68],
                                           int rq, int cu, float s[4][4]) {
#pragma unroll
    for (int i = 0; i < 4; ++i)
#pragma unroll
        for (int j = 0; j < 4; ++j) s[i][j] = 0.f;
#pragma unroll
    for (int k = 0; k < 64; k += 4) {
        float4 qv[4], kv[4];
#pragma unroll
        for (int i = 0; i < 4; ++i) qv[i] = *(const float4*)&Qs[rq * 4 + i][k];
#pragma unroll
        for (int j = 0; j < 4; ++j) kv[j] = *(const float4*)&Ks[j * 32 + cu][k];
#pragma unroll
        for (int i = 0; i < 4; ++i)
#pragma unroll
            for (int j = 0; j < 4; ++j)
                s[i][j] += qv[i].x * kv[j].x + qv[i].y * kv[j].y + qv[i].z * kv[j].z + qv[i].w * kv[j].w;
    }
}

__global__ __launch_bounds__(256) void attn_kernel(const float* __restrict__ qk,
                                                   const float* __restrict__ mask0,
                                                   const float* __restrict__ mask1,
                                                   u16* __restrict__ G,
                                                   float* __restrict__ out) {
    int a = blockIdx.z, b = blockIdx.y, tile = blockIdx.x;
    int mat = a * 2 + b;
    const float* mask = a ? mask1 : mask0;
    const size_t MS = (size_t)NB * NN_ * NH;
    const float* Q = qk + (size_t)(a * 2 + 0) * MS + (size_t)b * NN_ * NH;
    const float* K = qk + (size_t)(a * 2 + 1) * MS + (size_t)b * NN_ * NH;
    __shared__ float Qs[32][68];   // pad 4: 16B-aligned rows, banks spread
    __shared__ float Ks[128][68];
    __shared__ float redm[32][33];
    __shared__ float redsum[32][33];
    __shared__ float rowM[32], rowInv[32];
    int t = threadIdx.x;
    int rq = t >> 5, cu = t & 31;
    {
        const float4* Qsrc = (const float4*)(Q + (size_t)tile * 32 * NH);
        for (int i = t; i < 32 * 16; i += 256)
            *(float4*)&Qs[i >> 4][(i & 15) * 4] = Qsrc[i];
    }
    float mx[4], sm[4];
#pragma unroll
    for (int i = 0; i < 4; ++i) { mx[i] = -1e30f; sm[i] = 0.f; }
    // pass 1: online max + sum
    for (int c = 0; c < NN_ / 128; ++c) {
        __syncthreads();
        const float4* Ksrc = (const float4*)(K + (size_t)c * 128 * NH);
        for (int i = t; i < 128 * 16; i += 256)
            *(float4*)&Ks[i >> 4][(i & 15) * 4] = Ksrc[i];
        __syncthreads();
        float s[4][4];
        score_tile(Qs, Ks, rq, cu, s);
#pragma unroll
        for (int i = 0; i < 4; ++i) {
            int nrow = tile * 32 + rq * 4 + i;
#pragma unroll
            for (int j = 0; j < 4; ++j) {
                int m = c * 128 + j * 32 + cu;
                float sc = s[i][j] * 0.125f;
                float w = mask[(size_t)nrow * NN_ + m] + 1e-7f;
                if (sc > mx[i]) { sm[i] *= __expf(mx[i] - sc); mx[i] = sc; }
                sm[i] += w * __expf(sc - mx[i]);
            }
        }
    }
#pragma unroll
    for (int i = 0; i < 4; ++i) { redm[rq * 4 + i][cu] = mx[i]; redsum[rq * 4 + i][cu] = sm[i]; }
    __syncthreads();
    if (t < 32) {
        float M = -1e30f;
        for (int c2 = 0; c2 < 32; ++c2) M = fmaxf(M, redm[t][c2]);
        float S = 0.f;
        for (int c2 = 0; c2 < 32; ++c2) S += redsum[t][c2] * __expf(redm[t][c2] - M);
        rowM[t] = M;
        rowInv[t] = 1.f / S;   // S > 0 always (mask+1e-7 > 0)
    }
    __syncthreads();
    // pass 2: recompute, normalize, write bf16 G + fp32 first-order outputs
    for (int c = 0; c < NN_ / 128; ++c) {
        __syncthreads();
        const float4* Ksrc = (const float4*)(K + (size_t)c * 128 * NH);
        for (int i = t; i < 128 * 16; i += 256)
            *(float4*)&Ks[i >> 4][(i & 15) * 4] = Ksrc[i];
        __syncthreads();
        float s[4][4];
        score_tile(Qs, Ks, rq, cu, s);
#pragma unroll
        for (int i = 0; i < 4; ++i) {
            int nrow = tile * 32 + rq * 4 + i;
            float M = rowM[rq * 4 + i], inv = rowInv[rq * 4 + i];
            size_t ob = (size_t)(2 * a) * OUT_PER + ((size_t)b * NN_ + nrow) * (size_t)(3 * NN_);
#pragma unroll
            for (int j = 0; j < 4; ++j) {
                int m = c * 128 + j * 32 + cu;
                float sc = s[i][j] * 0.125f;
                float w = mask[(size_t)nrow * NN_ + m] + 1e-7f;
                float val = w * __expf(sc - M) * inv;
                G[(size_t)mat * NSQ + (size_t)nrow * NN_ + m] = f2bf(val);
                float ov = (m == nrow) ? 0.f : val;
                out[ob + m] = ov;
                out[ob + NN_ + m] = ov;
                out[ob + 2 * NN_ + m] = ov;
            }
        }
    }
}

// ---------------------------------------------------------------------------
// Kernel 3: 64x64 tiled transpose G -> GT (bf16), for MFMA B-operand rows.
// ---------------------------------------------------------------------------
__global__ __launch_bounds__(256) void transpose_kernel(const u16* __restrict__ G,
                                                        u16* __restrict__ GT) {
    __shared__ u16 tl[64][72];
    int t = threadIdx.x;
    int mat = blockIdx.z;
    int c0 = blockIdx.x * 64, r0 = blockIdx.y * 64;
    const u16* Gm = G + (size_t)mat * NSQ;
    u16* GTm = GT + (size_t)mat * NSQ;
#pragma unroll
    for (int i = 0; i < 2; ++i) {
        int v = t + 256 * i, row = v >> 3, seg = v & 7;
        *(uint4*)&tl[row][seg * 8] = *(const uint4*)&Gm[(size_t)(r0 + row) * NN_ + c0 + seg * 8];
    }
    __syncthreads();
#pragma unroll
    for (int i = 0; i < 2; ++i) {
        int v = t + 256 * i, cc = v >> 3, seg = v & 7;
        union { u16 h[8]; uint4 u; } tmp;
#pragma unroll
        for (int q = 0; q < 8; ++q) tmp.h[q] = tl[seg * 8 + q][cc];
        *(uint4*)&GTm[(size_t)(c0 + cc) * NN_ + r0 + seg * 8] = tmp.u;
    }
}

// ---------------------------------------------------------------------------
// Kernel 4: C = G @ G via bf16 MFMA 16x16x32; 128x128 block tile, 4 waves,
// 4x4 frags/wave; fp32 epilogue through LDS (two 64-row phases) -> float4
// stores, 3 localized copies, diag zeroed.
// ---------------------------------------------------------------------------
typedef __attribute__((ext_vector_type(8))) short bf8v;
typedef __attribute__((ext_vector_type(4))) float f4v;

__global__ __launch_bounds__(256) void matmul_kernel(const u16* __restrict__ G,
                                                     const u16* __restrict__ GT,
                                                     float* __restrict__ out) {
    __shared__ __align__(16) char smraw[64 * 132 * 4];  // 33792 B: A|B bf16 staging / fp32 C half-tile
    u16* smab = (u16*)smraw;
    float* smc = (float*)smraw;
    int t = threadIdx.x;
    int mat = blockIdx.z;
    int a = mat >> 1, b = mat & 1;
    int m0 = blockIdx.y * 128, n0 = blockIdx.x * 128;
    const u16* Gm = G + (size_t)mat * NSQ;
    const u16* GTm = GT + (size_t)mat * NSQ;
    int lane = t & 63, wv = t >> 6, wm = wv >> 1, wn = wv & 1;
    int m16 = lane & 15, quad = lane >> 4;
    f4v acc[4][4];
#pragma unroll
    for (int i = 0; i < 4; ++i)
#pragma unroll
        for (int j = 0; j < 4; ++j)
#pragma unroll
            for (int r = 0; r < 4; ++r) acc[i][j][r] = 0.f;

    for (int k0 = 0; k0 < NN_; k0 += 64) {
#pragma unroll
        for (int i = 0; i < 4; ++i) {
            int v = t + 256 * i, row = v >> 3, seg = v & 7;
            *(uint4*)&smab[row * 64 + seg * 8] =
                *(const uint4*)&Gm[(size_t)(m0 + row) * NN_ + k0 + seg * 8];
            *(uint4*)&smab[8192 + row * 64 + seg * 8] =
                *(const uint4*)&GTm[(size_t)(n0 + row) * NN_ + k0 + seg * 8];
        }
        __syncthreads();
#pragma unroll
        for (int kk = 0; kk < 64; kk += 32) {
            bf8v af[4], bfr[4];
#pragma unroll
            for (int i = 0; i < 4; ++i)
                af[i] = *(const bf8v*)&smab[(wm * 64 + i * 16 + m16) * 64 + kk + quad * 8];
#pragma unroll
            for (int j = 0; j < 4; ++j)
                bfr[j] = *(const bf8v*)&smab[8192 + (wn * 64 + j * 16 + m16) * 64 + kk + quad * 8];
#pragma unroll
            for (int i = 0; i < 4; ++i)
#pragma unroll
                for (int j = 0; j < 4; ++j)
                    acc[i][j] = __builtin_amdgcn_mfma_f32_16x16x32_bf16(af[i], bfr[j], acc[i][j], 0, 0, 0);
        }
        __syncthreads();
    }
    // epilogue: two 64-row phases through LDS (stride 132 -> only 2-way bank alias)
#pragma unroll
    for (int p = 0; p < 2; ++p) {
        __syncthreads();
        if (wm == p) {
#pragma unroll
            for (int i = 0; i < 4; ++i)
#pragma unroll
                for (int j = 0; j < 4; ++j)
#pragma unroll
                    for (int r = 0; r < 4; ++r)
                        smc[(i * 16 + quad * 4 + r) * 132 + wn * 64 + j * 16 + m16] = acc[i][j][r];
        }
        __syncthreads();
        size_t ob0 = (size_t)(2 * a + 1) * OUT_PER;
        for (int v = t; v < 64 * 32; v += 256) {
            int row = v >> 5, seg = v & 31;
            float4 vv = *(float4*)&smc[row * 132 + seg * 4];
            int grow = m0 + p * 64 + row;
            int gcol = n0 + seg * 4;
            if (grow >= gcol && grow < gcol + 4) ((float*)&vv)[grow - gcol] = 0.f;
            size_t ob = ob0 + ((size_t)b * NN_ + grow) * (size_t)(3 * NN_) + gcol;
            *(float4*)&out[ob] = vv;
            *(float4*)&out[ob + NN_] = vv;
            *(float4*)&out[ob + 2 * NN_] = vv;
        }
    }
}

// ---------------------------------------------------------------------------
extern "C" void kernel_launch(void* const* d_in, const int* in_sizes, int n_in,
                              void* d_out, int out_size, void* d_ws, size_t ws_size,
                              hipStream_t stream) {
    const float* hist = (const float*)d_in[0];
    const float* embd = (const float*)d_in[1];
    const float* embu = (const float*)d_in[2];
    const float* tid = (const float*)d_in[3];
    const float* diw = (const float*)d_in[4];
    const float* mask0 = (const float*)d_in[5];
    const float* mask1 = (const float*)d_in[6];
    const float* W1 = (const float*)d_in[7];
    const float* b1 = (const float*)d_in[8];
    const float* gamma = (const float*)d_in[9];
    const float* beta = (const float*)d_in[10];
    const float* mean = (const float*)d_in[11];
    const float* var = (const float*)d_in[12];
    const float* W2 = (const float*)d_in[13];
    const float* b2 = (const float*)d_in[14];
    const float* WQ = (const float*)d_in[15];
    const float* WK = (const float*)d_in[16];

    float* qk = (float*)d_ws;                                   // 4 MB fp32
    u16* G = (u16*)((char*)d_ws + (size_t)4 * 1024 * 1024);     // 33.5 MB bf16
    u16* GT = (u16*)((char*)d_ws + (size_t)4 * 1024 * 1024 + 4 * NSQ * sizeof(u16));
    float* out = (float*)d_out;

    feat_kernel<<<dim3(NB * NN_), dim3(128), 0, stream>>>(
        hist, embd, embu, tid, diw, W1, b1, gamma, beta, mean, var, W2, b2, WQ, WK, qk);
    attn_kernel<<<dim3(NN_ / 32, NB, 2), dim3(256), 0, stream>>>(qk, mask0, mask1, G, out);
    transpose_kernel<<<dim3(32, 32, 4), dim3(256), 0, stream>>>(G, GT);
    matmul_kernel<<<dim3(16, 16, 4), dim3(256), 0, stream>>>(G, GT, out);
}

// Round 3
// 641.066 us; speedup vs baseline: 1.1542x; 1.1542x over previous
//
#include <hip/hip_runtime.h>
#include <cstdint>

typedef unsigned short u16;

#define NB 2
#define NL 12
#define NN_ 2048
#define NH 64
#define NF 116
constexpr size_t NSQ = (size_t)NN_ * NN_;
constexpr size_t OUT_PER = (size_t)NB * NN_ * 3 * NN_;  // one output tensor (B,N,3N) elems

__device__ __forceinline__ u16 f2bf(float f) {
    union { float f; unsigned u; } v; v.f = f;
    unsigned r = 0x7FFFu + ((v.u >> 16) & 1u);
    return (u16)((v.u + r) >> 16);
}

// async global->LDS, 16B per lane; LDS dest must be wave-uniform base (+lane*16 implicit)
#define GLOAD_LDS16(g, l)                                                  \
    __builtin_amdgcn_global_load_lds(                                      \
        (const __attribute__((address_space(1))) unsigned int*)(g),        \
        (__attribute__((address_space(3))) unsigned int*)(l), 16, 0, 0)

// ---------------------------------------------------------------------------
// Kernel 1: per-(b,n) feature MLP -> Q/K vectors (fp32) for both adjacencies.
// qk layout: [(a*2 + qsel)][b][n][h], qsel 0=Q 1=K.  One 128-thr block per row.
// ---------------------------------------------------------------------------
__global__ __launch_bounds__(128) void feat_kernel(
    const float* __restrict__ hist, const float* __restrict__ embd, const float* __restrict__ embu,
    const float* __restrict__ tid, const float* __restrict__ diw,
    const float* __restrict__ W1, const float* __restrict__ b1,
    const float* __restrict__ gamma, const float* __restrict__ beta,
    const float* __restrict__ mean, const float* __restrict__ var,
    const float* __restrict__ W2, const float* __restrict__ b2,
    const float* __restrict__ WQ, const float* __restrict__ WK,
    float* __restrict__ qk) {
    int bn = blockIdx.x;
    int b = bn >> 11, n = bn & (NN_ - 1);
    __shared__ float X[NL];
    __shared__ float hsh[128];
    __shared__ float feat[84];
    int t = threadIdx.x;
    if (t < NL) X[t] = hist[((size_t)(b * NL + t) * NN_ + n) * 3];
    __syncthreads();
    float acc = b1[t];
#pragma unroll
    for (int l = 0; l < NL; ++l) acc += X[l] * W1[t * NL + l];
    acc = fmaxf(acc, 0.f);
    acc = (acc - mean[t]) * rsqrtf(var[t] + 1e-5f) * gamma[t] + beta[t];
    hsh[t] = acc;
    __syncthreads();
    if (t < 64) {
        float d = b2[t];
#pragma unroll 8
        for (int j = 0; j < 128; ++j) d += hsh[j] * W2[t * 128 + j];
        feat[t] = d;
    } else {
        int u = t - 64;
        if (u < 10) feat[64 + u] = tid[((size_t)(b * NL + (NL - 1)) * NN_ + n) * 10 + u];
        else if (u < 20) feat[64 + u] = diw[((size_t)(b * NL + (NL - 1)) * NN_ + n) * 10 + (u - 10)];
    }
    __syncthreads();
    const float* W = (t < 64) ? WQ : WK;
    int row = t & 63;
    float s = 0.f;
    for (int f = 0; f < 84; ++f) s += feat[f] * W[row * NF + f];
    float s1 = s, s2 = s;
    for (int u2 = 0; u2 < 32; ++u2) {
        float w = W[row * NF + 84 + u2];
        s1 += w * embd[n * 32 + u2];
        s2 += w * embu[n * 32 + u2];
    }
    int qsel = (t < 64) ? 0 : 1;
    const size_t MS = (size_t)NB * NN_ * NH;
    size_t base = ((size_t)b * NN_ + n) * NH + row;
    qk[(size_t)(0 * 2 + qsel) * MS + base] = s1;
    qk[(size_t)(1 * 2 + qsel) * MS + base] = s2;
}

// ---------------------------------------------------------------------------
// Kernel 2: scores GEMM — S[mat][n][m] = (Q . K) / 8, computed ONCE.
// Block tile 64(n) x 128(m), K=64 full. 256 thr, thread tile 8 rows x 4 cols
// (cols j*32+cu -> coalesced scalar writes; K-row LDS reads lane-stride 1 row).
// ---------------------------------------------------------------------------
__global__ __launch_bounds__(256) void scores_kernel(const float* __restrict__ qk,
                                                     float* __restrict__ S) {
    int mat = blockIdx.z;
    int a = mat >> 1, b = mat & 1;
    const size_t MS = (size_t)NB * NN_ * NH;
    const float* Q = qk + (size_t)(a * 2 + 0) * MS + (size_t)b * NN_ * NH;
    const float* K = qk + (size_t)(a * 2 + 1) * MS + (size_t)b * NN_ * NH;
    int n0 = blockIdx.y * 64;
    int m0 = blockIdx.x * 128;
    __shared__ float Qs[64][68];
    __shared__ float Ks[128][68];
    int t = threadIdx.x;
    {
        const float4* Qsrc = (const float4*)(Q + (size_t)n0 * NH);
        for (int i = t; i < 64 * 16; i += 256)
            *(float4*)&Qs[i >> 4][(i & 15) * 4] = Qsrc[i];
        const float4* Ksrc = (const float4*)(K + (size_t)m0 * NH);
        for (int i = t; i < 128 * 16; i += 256)
            *(float4*)&Ks[i >> 4][(i & 15) * 4] = Ksrc[i];
    }
    __syncthreads();
    int rq = t >> 5, cu = t & 31;
    float acc[8][4];
#pragma unroll
    for (int i = 0; i < 8; ++i)
#pragma unroll
        for (int j = 0; j < 4; ++j) acc[i][j] = 0.f;
#pragma unroll
    for (int kc = 0; kc < 16; ++kc) {
        float4 qv[8], kv[4];
#pragma unroll
        for (int i = 0; i < 8; ++i) qv[i] = *(const float4*)&Qs[rq * 8 + i][kc * 4];
#pragma unroll
        for (int j = 0; j < 4; ++j) kv[j] = *(const float4*)&Ks[j * 32 + cu][kc * 4];
#pragma unroll
        for (int i = 0; i < 8; ++i)
#pragma unroll
            for (int j = 0; j < 4; ++j)
                acc[i][j] += qv[i].x * kv[j].x + qv[i].y * kv[j].y + qv[i].z * kv[j].z + qv[i].w * kv[j].w;
    }
    float* Sm = S + (size_t)mat * NSQ;
#pragma unroll
    for (int i = 0; i < 8; ++i) {
        size_t rb = (size_t)(n0 + rq * 8 + i) * NN_ + m0;
#pragma unroll
        for (int j = 0; j < 4; ++j) Sm[rb + j * 32 + cu] = acc[i][j] * 0.125f;
    }
}

// ---------------------------------------------------------------------------
// Kernel 3: row normalize — one block per (mat,row). Row slice in registers:
// max-reduce, w=(mask+1e-7)*exp(s-M) once, sum-reduce, write G bf16 (w/ diag)
// and first-order fp32 outputs (3 copies, diag zeroed).
// Softmax denom cancels with row-norm, so A = w / sum(w).
// ---------------------------------------------------------------------------
__global__ __launch_bounds__(256) void normalize_kernel(const float* __restrict__ S,
                                                        const float* __restrict__ mask0,
                                                        const float* __restrict__ mask1,
                                                        u16* __restrict__ G,
                                                        float* __restrict__ out) {
    int n = blockIdx.x;
    int mat = blockIdx.y;
    int a = mat >> 1, b = mat & 1;
    const float* mask = a ? mask1 : mask0;
    const float* Srow = S + ((size_t)mat * NN_ + n) * NN_;
    const float* Mrow = mask + (size_t)n * NN_;
    int t = threadIdx.x;
    int c0 = t * 8;
    float4 s0 = *(const float4*)&Srow[c0];
    float4 s1 = *(const float4*)&Srow[c0 + 4];
    float4 k0 = *(const float4*)&Mrow[c0];
    float4 k1 = *(const float4*)&Mrow[c0 + 4];
    float sv[8] = {s0.x, s0.y, s0.z, s0.w, s1.x, s1.y, s1.z, s1.w};
    float mv[8] = {k0.x, k0.y, k0.z, k0.w, k1.x, k1.y, k1.z, k1.w};
    float mx = sv[0];
#pragma unroll
    for (int i = 1; i < 8; ++i) mx = fmaxf(mx, sv[i]);
#pragma unroll
    for (int off = 32; off >= 1; off >>= 1) mx = fmaxf(mx, __shfl_xor(mx, off, 64));
    __shared__ float redA[4], redB[4];
    int wv = t >> 6;
    if ((t & 63) == 0) redA[wv] = mx;
    __syncthreads();
    mx = fmaxf(fmaxf(redA[0], redA[1]), fmaxf(redA[2], redA[3]));
    float w[8];
    float sum = 0.f;
#pragma unroll
    for (int i = 0; i < 8; ++i) {
        w[i] = (mv[i] + 1e-7f) * __expf(sv[i] - mx);
        sum += w[i];
    }
#pragma unroll
    for (int off = 32; off >= 1; off >>= 1) sum += __shfl_xor(sum, off, 64);
    if ((t & 63) == 0) redB[wv] = sum;
    __syncthreads();
    float inv = 1.f / (redB[0] + redB[1] + redB[2] + redB[3]);
    // G (with diagonal) bf16
    union { u16 h[8]; uint4 u; } gv;
    float ov[8];
#pragma unroll
    for (int i = 0; i < 8; ++i) {
        float val = w[i] * inv;
        gv.h[i] = f2bf(val);
        ov[i] = (c0 + i == n) ? 0.f : val;
    }
    *(uint4*)&G[((size_t)mat * NSQ + (size_t)n * NN_) + c0] = gv.u;
    size_t ob = (size_t)(2 * a) * OUT_PER + ((size_t)b * NN_ + n) * (size_t)(3 * NN_) + c0;
    float4 o0 = {ov[0], ov[1], ov[2], ov[3]};
    float4 o1 = {ov[4], ov[5], ov[6], ov[7]};
    *(float4*)&out[ob] = o0;        *(float4*)&out[ob + 4] = o1;
    *(float4*)&out[ob + NN_] = o0;  *(float4*)&out[ob + NN_ + 4] = o1;
    *(float4*)&out[ob + 2 * NN_] = o0; *(float4*)&out[ob + 2 * NN_ + 4] = o1;
}

// ---------------------------------------------------------------------------
// Kernel 4: 64x64 tiled transpose G -> GT (bf16), for MFMA B-operand rows.
// ---------------------------------------------------------------------------
__global__ __launch_bounds__(256) void transpose_kernel(const u16* __restrict__ G,
                                                        u16* __restrict__ GT) {
    __shared__ u16 tl[64][72];
    int t = threadIdx.x;
    int mat = blockIdx.z;
    int c0 = blockIdx.x * 64, r0 = blockIdx.y * 64;
    const u16* Gm = G + (size_t)mat * NSQ;
    u16* GTm = GT + (size_t)mat * NSQ;
#pragma unroll
    for (int i = 0; i < 2; ++i) {
        int v = t + 256 * i, row = v >> 3, seg = v & 7;
        *(uint4*)&tl[row][seg * 8] = *(const uint4*)&Gm[(size_t)(r0 + row) * NN_ + c0 + seg * 8];
    }
    __syncthreads();
#pragma unroll
    for (int i = 0; i < 2; ++i) {
        int v = t + 256 * i, cc = v >> 3, seg = v & 7;
        union { u16 h[8]; uint4 u; } tmp;
#pragma unroll
        for (int q = 0; q < 8; ++q) tmp.h[q] = tl[seg * 8 + q][cc];
        *(uint4*)&GTm[(size_t)(c0 + cc) * NN_ + r0 + seg * 8] = tmp.u;
    }
}

// ---------------------------------------------------------------------------
// Kernel 5: C = G @ G via bf16 MFMA 16x16x32; 128x128 block tile, 4 waves,
// 4x4 frags/wave; staging via global_load_lds width=16 (m97 pattern);
// fp32 epilogue through LDS (two 64-row phases) -> float4 stores, 3 copies.
// ---------------------------------------------------------------------------
typedef __attribute__((ext_vector_type(8))) short bf8v;
typedef __attribute__((ext_vector_type(4))) float f4v;

__global__ __launch_bounds__(256) void matmul_kernel(const u16* __restrict__ G,
                                                     const u16* __restrict__ GT,
                                                     float* __restrict__ out) {
    __shared__ __align__(16) char smraw[64 * 132 * 4];  // staging 32KB / fp32 C half-tile 33792B
    u16* smab = (u16*)smraw;
    float* smc = (float*)smraw;
    int t = threadIdx.x;
    int mat = blockIdx.z;
    int a = mat >> 1, b = mat & 1;
    int m0 = blockIdx.y * 128, n0 = blockIdx.x * 128;
    const u16* Gm = G + (size_t)mat * NSQ;
    const u16* GTm = GT + (size_t)mat * NSQ;
    int lane = t & 63, wv = t >> 6, wm = wv >> 1, wn = wv & 1;
    int m16 = lane & 15, quad = lane >> 4;
    int lrow = lane >> 3, lseg = lane & 7;  // 8 rows x 8 segs per wave chunk
    f4v acc[4][4];
#pragma unroll
    for (int i = 0; i < 4; ++i)
#pragma unroll
        for (int j = 0; j < 4; ++j)
#pragma unroll
            for (int r = 0; r < 4; ++r) acc[i][j][r] = 0.f;

    for (int k0 = 0; k0 < NN_; k0 += 64) {
#pragma unroll
        for (int i = 0; i < 4; ++i) {
            int r0 = wv * 32 + i * 8;
            const u16* ga = Gm + (size_t)(m0 + r0 + lrow) * NN_ + k0 + lseg * 8;
            GLOAD_LDS16(ga, &smab[r0 * 64]);
            const u16* gb = GTm + (size_t)(n0 + r0 + lrow) * NN_ + k0 + lseg * 8;
            GLOAD_LDS16(gb, &smab[8192 + r0 * 64]);
        }
        __syncthreads();
#pragma unroll
        for (int kk = 0; kk < 64; kk += 32) {
            bf8v af[4], bfr[4];
#pragma unroll
            for (int i = 0; i < 4; ++i)
                af[i] = *(const bf8v*)&smab[(wm * 64 + i * 16 + m16) * 64 + kk + quad * 8];
#pragma unroll
            for (int j = 0; j < 4; ++j)
                bfr[j] = *(const bf8v*)&smab[8192 + (wn * 64 + j * 16 + m16) * 64 + kk + quad * 8];
#pragma unroll
            for (int i = 0; i < 4; ++i)
#pragma unroll
                for (int j = 0; j < 4; ++j)
                    acc[i][j] = __builtin_amdgcn_mfma_f32_16x16x32_bf16(af[i], bfr[j], acc[i][j], 0, 0, 0);
        }
        __syncthreads();
    }
    // epilogue: two 64-row phases through LDS (stride 132 -> 2-way alias = free)
#pragma unroll
    for (int p = 0; p < 2; ++p) {
        __syncthreads();
        if (wm == p) {
#pragma unroll
            for (int i = 0; i < 4; ++i)
#pragma unroll
                for (int j = 0; j < 4; ++j)
#pragma unroll
                    for (int r = 0; r < 4; ++r)
                        smc[(i * 16 + quad * 4 + r) * 132 + wn * 64 + j * 16 + m16] = acc[i][j][r];
        }
        __syncthreads();
        size_t ob0 = (size_t)(2 * a + 1) * OUT_PER;
        for (int v = t; v < 64 * 32; v += 256) {
            int row = v >> 5, seg = v & 31;
            float4 vv = *(float4*)&smc[row * 132 + seg * 4];
            int grow = m0 + p * 64 + row;
            int gcol = n0 + seg * 4;
            if (grow >= gcol && grow < gcol + 4) ((float*)&vv)[grow - gcol] = 0.f;
            size_t ob = ob0 + ((size_t)b * NN_ + grow) * (size_t)(3 * NN_) + gcol;
            *(float4*)&out[ob] = vv;
            *(float4*)&out[ob + NN_] = vv;
            *(float4*)&out[ob + 2 * NN_] = vv;
        }
    }
}

// ---------------------------------------------------------------------------
extern "C" void kernel_launch(void* const* d_in, const int* in_sizes, int n_in,
                              void* d_out, int out_size, void* d_ws, size_t ws_size,
                              hipStream_t stream) {
    const float* hist = (const float*)d_in[0];
    const float* embd = (const float*)d_in[1];
    const float* embu = (const float*)d_in[2];
    const float* tid = (const float*)d_in[3];
    const float* diw = (const float*)d_in[4];
    const float* mask0 = (const float*)d_in[5];
    const float* mask1 = (const float*)d_in[6];
    const float* W1 = (const float*)d_in[7];
    const float* b1 = (const float*)d_in[8];
    const float* gamma = (const float*)d_in[9];
    const float* beta = (const float*)d_in[10];
    const float* mean = (const float*)d_in[11];
    const float* var = (const float*)d_in[12];
    const float* W2 = (const float*)d_in[13];
    const float* b2 = (const float*)d_in[14];
    const float* WQ = (const float*)d_in[15];
    const float* WK = (const float*)d_in[16];

    char* ws = (char*)d_ws;
    float* qk = (float*)ws;                                   // 4.2 MB fp32
    float* S  = (float*)(ws + (size_t)8 * 1024 * 1024);       // 67.1 MB fp32
    u16* G    = (u16*)(ws + (size_t)80 * 1024 * 1024);        // 33.6 MB bf16
    u16* GT   = (u16*)(ws + (size_t)116 * 1024 * 1024);       // 33.6 MB bf16
    float* out = (float*)d_out;

    feat_kernel<<<dim3(NB * NN_), dim3(128), 0, stream>>>(
        hist, embd, embu, tid, diw, W1, b1, gamma, beta, mean, var, W2, b2, WQ, WK, qk);
    scores_kernel<<<dim3(16, 32, 4), dim3(256), 0, stream>>>(qk, S);
    normalize_kernel<<<dim3(NN_, 4), dim3(256), 0, stream>>>(S, mask0, mask1, G, out);
    transpose_kernel<<<dim3(32, 32, 4), dim3(256), 0, stream>>>(G, GT);
    matmul_kernel<<<dim3(16, 16, 4), dim3(256), 0, stream>>>(G, GT, out);
}

// Round 4
// 617.795 us; speedup vs baseline: 1.1976x; 1.0377x over previous
//
#include <hip/hip_runtime.h>
#include <cstdint>

typedef unsigned short u16;

#define NB 2
#define NL 12
#define NN_ 2048
#define NH 64
#define NF 116
constexpr size_t NSQ = (size_t)NN_ * NN_;
constexpr size_t OUT_PER = (size_t)NB * NN_ * 3 * NN_;  // one output tensor (B,N,3N) elems

__device__ __forceinline__ u16 f2bf(float f) {
    union { float f; unsigned u; } v; v.f = f;
    unsigned r = 0x7FFFu + ((v.u >> 16) & 1u);
    return (u16)((v.u + r) >> 16);
}

// async global->LDS, 16B per lane; LDS dest must be wave-uniform base (+lane*16 implicit)
#define GLOAD_LDS16(g, l)                                                  \
    __builtin_amdgcn_global_load_lds(                                      \
        (const __attribute__((address_space(1))) unsigned int*)(g),        \
        (__attribute__((address_space(3))) unsigned int*)(l), 16, 0, 0)

__device__ __forceinline__ float dot4(float4 a, float4 b) {
    return a.x * b.x + a.y * b.y + a.z * b.z + a.w * b.w;
}

// ---------------------------------------------------------------------------
// Kernel 1: per-(b,n) feature MLP -> Q/K vectors (fp32) for both adjacencies.
// qk layout: [(a*2 + qsel)][b][n][h], qsel 0=Q 1=K.  One 128-thr block per row.
// Weight rows are 16B-aligned (NF*4=464B, 128*4B): float4 loads throughout.
// ---------------------------------------------------------------------------
__global__ __launch_bounds__(128) void feat_kernel(
    const float* __restrict__ hist, const float* __restrict__ embd, const float* __restrict__ embu,
    const float* __restrict__ tid, const float* __restrict__ diw,
    const float* __restrict__ W1, const float* __restrict__ b1,
    const float* __restrict__ gamma, const float* __restrict__ beta,
    const float* __restrict__ mean, const float* __restrict__ var,
    const float* __restrict__ W2, const float* __restrict__ b2,
    const float* __restrict__ WQ, const float* __restrict__ WK,
    float* __restrict__ qk) {
    int bn = blockIdx.x;
    int b = bn >> 11, n = bn & (NN_ - 1);
    __shared__ __align__(16) float X[NL];
    __shared__ __align__(16) float hsh[128];
    __shared__ __align__(16) float feat[84];
    int t = threadIdx.x;
    if (t < NL) X[t] = hist[((size_t)(b * NL + t) * NN_ + n) * 3];
    __syncthreads();
    float acc = b1[t];
#pragma unroll
    for (int l = 0; l < NL; ++l) acc += X[l] * W1[t * NL + l];
    acc = fmaxf(acc, 0.f);
    acc = (acc - mean[t]) * rsqrtf(var[t] + 1e-5f) * gamma[t] + beta[t];
    hsh[t] = acc;
    __syncthreads();
    if (t < 64) {
        float d = b2[t];
        const float4* w2v = (const float4*)(W2 + t * 128);
#pragma unroll 8
        for (int j = 0; j < 32; ++j) d += dot4(w2v[j], *(const float4*)&hsh[j * 4]);
        feat[t] = d;
    } else {
        int u = t - 64;
        if (u < 10) feat[64 + u] = tid[((size_t)(b * NL + (NL - 1)) * NN_ + n) * 10 + u];
        else if (u < 20) feat[64 + u] = diw[((size_t)(b * NL + (NL - 1)) * NN_ + n) * 10 + (u - 10)];
    }
    __syncthreads();
    const float* W = (t < 64) ? WQ : WK;
    int row = t & 63;
    const float4* Wv = (const float4*)(W + row * NF);  // 464B rows -> 16B aligned
    float s = 0.f;
#pragma unroll
    for (int f = 0; f < 21; ++f) s += dot4(Wv[f], *(const float4*)&feat[f * 4]);
    float s1 = s, s2 = s;
    const float4* e1 = (const float4*)(embd + n * 32);
    const float4* e2 = (const float4*)(embu + n * 32);
#pragma unroll
    for (int u2 = 0; u2 < 8; ++u2) {
        float4 wv = Wv[21 + u2];
        s1 += dot4(wv, e1[u2]);
        s2 += dot4(wv, e2[u2]);
    }
    int qsel = (t < 64) ? 0 : 1;
    const size_t MS = (size_t)NB * NN_ * NH;
    size_t base = ((size_t)b * NN_ + n) * NH + row;
    qk[(size_t)(0 * 2 + qsel) * MS + base] = s1;
    qk[(size_t)(1 * 2 + qsel) * MS + base] = s2;
}

// ---------------------------------------------------------------------------
// Kernel 2: scores GEMM — S[mat][n][m] = (Q . K) / 8, computed ONCE.
// Block tile 64(n) x 128(m), K=64 full. 256 thr, thread tile 8 rows x 4 cols.
// ---------------------------------------------------------------------------
__global__ __launch_bounds__(256) void scores_kernel(const float* __restrict__ qk,
                                                     float* __restrict__ S) {
    int mat = blockIdx.z;
    int a = mat >> 1, b = mat & 1;
    const size_t MS = (size_t)NB * NN_ * NH;
    const float* Q = qk + (size_t)(a * 2 + 0) * MS + (size_t)b * NN_ * NH;
    const float* K = qk + (size_t)(a * 2 + 1) * MS + (size_t)b * NN_ * NH;
    int n0 = blockIdx.y * 64;
    int m0 = blockIdx.x * 128;
    __shared__ float Qs[64][68];
    __shared__ float Ks[128][68];
    int t = threadIdx.x;
    {
        const float4* Qsrc = (const float4*)(Q + (size_t)n0 * NH);
        for (int i = t; i < 64 * 16; i += 256)
            *(float4*)&Qs[i >> 4][(i & 15) * 4] = Qsrc[i];
        const float4* Ksrc = (const float4*)(K + (size_t)m0 * NH);
        for (int i = t; i < 128 * 16; i += 256)
            *(float4*)&Ks[i >> 4][(i & 15) * 4] = Ksrc[i];
    }
    __syncthreads();
    int rq = t >> 5, cu = t & 31;
    float acc[8][4];
#pragma unroll
    for (int i = 0; i < 8; ++i)
#pragma unroll
        for (int j = 0; j < 4; ++j) acc[i][j] = 0.f;
#pragma unroll
    for (int kc = 0; kc < 16; ++kc) {
        float4 qv[8], kv[4];
#pragma unroll
        for (int i = 0; i < 8; ++i) qv[i] = *(const float4*)&Qs[rq * 8 + i][kc * 4];
#pragma unroll
        for (int j = 0; j < 4; ++j) kv[j] = *(const float4*)&Ks[j * 32 + cu][kc * 4];
#pragma unroll
        for (int i = 0; i < 8; ++i)
#pragma unroll
            for (int j = 0; j < 4; ++j) acc[i][j] += dot4(qv[i], kv[j]);
    }
    float* Sm = S + (size_t)mat * NSQ;
#pragma unroll
    for (int i = 0; i < 8; ++i) {
        size_t rb = (size_t)(n0 + rq * 8 + i) * NN_ + m0;
#pragma unroll
        for (int j = 0; j < 4; ++j) Sm[rb + j * 32 + cu] = acc[i][j] * 0.125f;
    }
}

// ---------------------------------------------------------------------------
// Kernel 3: row normalize — one block per (mat,row). Row slice in registers:
// max-reduce, w=(mask+1e-7)*exp(s-M) once, sum-reduce, write G bf16 (w/ diag)
// and first-order fp32 outputs (3 copies, diag zeroed).
// Softmax denom cancels with row-norm, so A = w / sum(w).
// ---------------------------------------------------------------------------
__global__ __launch_bounds__(256) void normalize_kernel(const float* __restrict__ S,
                                                        const float* __restrict__ mask0,
                                                        const float* __restrict__ mask1,
                                                        u16* __restrict__ G,
                                                        float* __restrict__ out) {
    int n = blockIdx.x;
    int mat = blockIdx.y;
    int a = mat >> 1, b = mat & 1;
    const float* mask = a ? mask1 : mask0;
    const float* Srow = S + ((size_t)mat * NN_ + n) * NN_;
    const float* Mrow = mask + (size_t)n * NN_;
    int t = threadIdx.x;
    int c0 = t * 8;
    float4 s0 = *(const float4*)&Srow[c0];
    float4 s1 = *(const float4*)&Srow[c0 + 4];
    float4 k0 = *(const float4*)&Mrow[c0];
    float4 k1 = *(const float4*)&Mrow[c0 + 4];
    float sv[8] = {s0.x, s0.y, s0.z, s0.w, s1.x, s1.y, s1.z, s1.w};
    float mv[8] = {k0.x, k0.y, k0.z, k0.w, k1.x, k1.y, k1.z, k1.w};
    float mx = sv[0];
#pragma unroll
    for (int i = 1; i < 8; ++i) mx = fmaxf(mx, sv[i]);
#pragma unroll
    for (int off = 32; off >= 1; off >>= 1) mx = fmaxf(mx, __shfl_xor(mx, off, 64));
    __shared__ float redA[4], redB[4];
    int wv = t >> 6;
    if ((t & 63) == 0) redA[wv] = mx;
    __syncthreads();
    mx = fmaxf(fmaxf(redA[0], redA[1]), fmaxf(redA[2], redA[3]));
    float w[8];
    float sum = 0.f;
#pragma unroll
    for (int i = 0; i < 8; ++i) {
        w[i] = (mv[i] + 1e-7f) * __expf(sv[i] - mx);
        sum += w[i];
    }
#pragma unroll
    for (int off = 32; off >= 1; off >>= 1) sum += __shfl_xor(sum, off, 64);
    if ((t & 63) == 0) redB[wv] = sum;
    __syncthreads();
    float inv = 1.f / (redB[0] + redB[1] + redB[2] + redB[3]);
    union { u16 h[8]; uint4 u; } gv;
    float ov[8];
#pragma unroll
    for (int i = 0; i < 8; ++i) {
        float val = w[i] * inv;
        gv.h[i] = f2bf(val);
        ov[i] = (c0 + i == n) ? 0.f : val;
    }
    *(uint4*)&G[((size_t)mat * NSQ + (size_t)n * NN_) + c0] = gv.u;
    size_t ob = (size_t)(2 * a) * OUT_PER + ((size_t)b * NN_ + n) * (size_t)(3 * NN_) + c0;
    float4 o0 = {ov[0], ov[1], ov[2], ov[3]};
    float4 o1 = {ov[4], ov[5], ov[6], ov[7]};
    *(float4*)&out[ob] = o0;        *(float4*)&out[ob + 4] = o1;
    *(float4*)&out[ob + NN_] = o0;  *(float4*)&out[ob + NN_ + 4] = o1;
    *(float4*)&out[ob + 2 * NN_] = o0; *(float4*)&out[ob + 2 * NN_ + 4] = o1;
}

// ---------------------------------------------------------------------------
// Kernel 4: 64x64 tiled transpose G -> GT (bf16), for MFMA B-operand rows.
// ---------------------------------------------------------------------------
__global__ __launch_bounds__(256) void transpose_kernel(const u16* __restrict__ G,
                                                        u16* __restrict__ GT) {
    __shared__ u16 tl[64][72];
    int t = threadIdx.x;
    int mat = blockIdx.z;
    int c0 = blockIdx.x * 64, r0 = blockIdx.y * 64;
    const u16* Gm = G + (size_t)mat * NSQ;
    u16* GTm = GT + (size_t)mat * NSQ;
#pragma unroll
    for (int i = 0; i < 2; ++i) {
        int v = t + 256 * i, row = v >> 3, seg = v & 7;
        *(uint4*)&tl[row][seg * 8] = *(const uint4*)&Gm[(size_t)(r0 + row) * NN_ + c0 + seg * 8];
    }
    __syncthreads();
#pragma unroll
    for (int i = 0; i < 2; ++i) {
        int v = t + 256 * i, cc = v >> 3, seg = v & 7;
        union { u16 h[8]; uint4 u; } tmp;
#pragma unroll
        for (int q = 0; q < 8; ++q) tmp.h[q] = tl[seg * 8 + q][cc];
        *(uint4*)&GTm[(size_t)(c0 + cc) * NN_ + r0 + seg * 8] = tmp.u;
    }
}

// ---------------------------------------------------------------------------
// Kernel 5: C = G @ G via bf16 MFMA 16x16x32; BM=256 x BN=128 block tile
// (cuts global operand fetch 25% vs 128x128), 256 thr / 4 waves, each wave
// a 128x64 C-tile (8x4 frags). Staging via global_load_lds width=16.
// fp32 epilogue through LDS in four 64-row phases -> float4 stores, 3 copies.
// ---------------------------------------------------------------------------
typedef __attribute__((ext_vector_type(8))) short bf8v;
typedef __attribute__((ext_vector_type(4))) float f4v;

#define BM 256
#define BN 128

__global__ __launch_bounds__(256, 2) void matmul_kernel(const u16* __restrict__ G,
                                                        const u16* __restrict__ GT,
                                                        float* __restrict__ out) {
    __shared__ __align__(16) char smraw[49152];   // A 32KB | B 16KB ; epilogue 64x132 fp32
    u16* smA = (u16*)smraw;                       // [256][64]
    u16* smB = (u16*)(smraw + 32768);             // [128][64]
    float* smc = (float*)smraw;
    int t = threadIdx.x;
    int mat = blockIdx.z;
    int a = mat >> 1, b = mat & 1;
    int m0 = blockIdx.y * BM, n0 = blockIdx.x * BN;
    const u16* Gm = G + (size_t)mat * NSQ;
    const u16* GTm = GT + (size_t)mat * NSQ;
    int lane = t & 63, wv = t >> 6;
    int wm = wv >> 1, wn = wv & 1;                // wave grid 2x2, wave tile 128x64
    int m16 = lane & 15, quad = lane >> 4;
    int lrow = lane >> 3, lseg = lane & 7;        // 8 rows x 8 segs per staging instr
    f4v acc[8][4];
#pragma unroll
    for (int i = 0; i < 8; ++i)
#pragma unroll
        for (int j = 0; j < 4; ++j)
#pragma unroll
            for (int r = 0; r < 4; ++r) acc[i][j][r] = 0.f;

    for (int k0 = 0; k0 < NN_; k0 += 64) {
#pragma unroll
        for (int i = 0; i < 8; ++i) {             // A: 256 rows
            int r0 = wv * 64 + i * 8;
            GLOAD_LDS16(Gm + (size_t)(m0 + r0 + lrow) * NN_ + k0 + lseg * 8, &smA[r0 * 64]);
        }
#pragma unroll
        for (int i = 0; i < 4; ++i) {             // B: 128 rows
            int r0 = wv * 32 + i * 8;
            GLOAD_LDS16(GTm + (size_t)(n0 + r0 + lrow) * NN_ + k0 + lseg * 8, &smB[r0 * 64]);
        }
        __syncthreads();
#pragma unroll
        for (int kk = 0; kk < 64; kk += 32) {
            bf8v af[8], bfr[4];
#pragma unroll
            for (int i = 0; i < 8; ++i)
                af[i] = *(const bf8v*)&smA[(wm * 128 + i * 16 + m16) * 64 + kk + quad * 8];
#pragma unroll
            for (int j = 0; j < 4; ++j)
                bfr[j] = *(const bf8v*)&smB[(wn * 64 + j * 16 + m16) * 64 + kk + quad * 8];
#pragma unroll
            for (int i = 0; i < 8; ++i)
#pragma unroll
                for (int j = 0; j < 4; ++j)
                    acc[i][j] = __builtin_amdgcn_mfma_f32_16x16x32_bf16(af[i], bfr[j], acc[i][j], 0, 0, 0);
        }
        __syncthreads();
    }
    // epilogue: four 64-row phases through LDS (stride 132 -> 2-way alias = free)
#pragma unroll
    for (int p = 0; p < 4; ++p) {
        __syncthreads();
        if (wm == (p >> 1)) {
#pragma unroll
            for (int i2 = 0; i2 < 4; ++i2) {
                int i = (p & 1) * 4 + i2;
#pragma unroll
                for (int j = 0; j < 4; ++j)
#pragma unroll
                    for (int r = 0; r < 4; ++r)
                        smc[(i2 * 16 + quad * 4 + r) * 132 + wn * 64 + j * 16 + m16] = acc[i][j][r];
            }
        }
        __syncthreads();
        size_t ob0 = (size_t)(2 * a + 1) * OUT_PER;
        for (int v = t; v < 64 * 32; v += 256) {
            int row = v >> 5, seg = v & 31;
            float4 vv = *(float4*)&smc[row * 132 + seg * 4];
            int grow = m0 + p * 64 + row;
            int gcol = n0 + seg * 4;
            if (grow >= gcol && grow < gcol + 4) ((float*)&vv)[grow - gcol] = 0.f;
            size_t ob = ob0 + ((size_t)b * NN_ + grow) * (size_t)(3 * NN_) + gcol;
            *(float4*)&out[ob] = vv;
            *(float4*)&out[ob + NN_] = vv;
            *(float4*)&out[ob + 2 * NN_] = vv;
        }
    }
}

// ---------------------------------------------------------------------------
extern "C" void kernel_launch(void* const* d_in, const int* in_sizes, int n_in,
                              void* d_out, int out_size, void* d_ws, size_t ws_size,
                              hipStream_t stream) {
    const float* hist = (const float*)d_in[0];
    const float* embd = (const float*)d_in[1];
    const float* embu = (const float*)d_in[2];
    const float* tid = (const float*)d_in[3];
    const float* diw = (const float*)d_in[4];
    const float* mask0 = (const float*)d_in[5];
    const float* mask1 = (const float*)d_in[6];
    const float* W1 = (const float*)d_in[7];
    const float* b1 = (const float*)d_in[8];
    const float* gamma = (const float*)d_in[9];
    const float* beta = (const float*)d_in[10];
    const float* mean = (const float*)d_in[11];
    const float* var = (const float*)d_in[12];
    const float* W2 = (const float*)d_in[13];
    const float* b2 = (const float*)d_in[14];
    const float* WQ = (const float*)d_in[15];
    const float* WK = (const float*)d_in[16];

    char* ws = (char*)d_ws;
    float* qk = (float*)ws;                                   // 4.2 MB fp32
    float* S  = (float*)(ws + (size_t)8 * 1024 * 1024);       // 67.1 MB fp32
    u16* G    = (u16*)(ws + (size_t)80 * 1024 * 1024);        // 33.6 MB bf16
    u16* GT   = (u16*)(ws + (size_t)116 * 1024 * 1024);       // 33.6 MB bf16
    float* out = (float*)d_out;

    feat_kernel<<<dim3(NB * NN_), dim3(128), 0, stream>>>(
        hist, embd, embu, tid, diw, W1, b1, gamma, beta, mean, var, W2, b2, WQ, WK, qk);
    scores_kernel<<<dim3(16, 32, 4), dim3(256), 0, stream>>>(qk, S);
    normalize_kernel<<<dim3(NN_, 4), dim3(256), 0, stream>>>(S, mask0, mask1, G, out);
    transpose_kernel<<<dim3(32, 32, 4), dim3(256), 0, stream>>>(G, GT);
    matmul_kernel<<<dim3(NN_ / BN, NN_ / BM, 4), dim3(256), 0, stream>>>(G, GT, out);
}